// Round 5
// baseline (622.952 us; speedup 1.0000x reference)
//
#include <hip/hip_runtime.h>
#include <hip/hip_bf16.h>
#include <math.h>

// ---------------------------------------------------------------------------
// FeatureNet (DGCNN edge-conv block), MI355X / gfx950, f32, round 5.
//
// Round-5 change: conv GEMM restructured so W comes from the SCALAR pipe
// (wave-uniform s_load via readfirstlane-pinned base) and only H touches LDS
// (2 conflict-free ds_read_b32 per c-step). Wave = 32d x 128p, lane = p.
// kNN LDS switched to 4 b32 planes (kills the b128 8-way conflict).
// ---------------------------------------------------------------------------

#define B_   16
#define N_   2048
#define KNN  8
#define DIM  128
#define P_   (B_*N_*KNN)   // 262144
#define CAP  128           // compacted candidate capacity per point

// ws layout (bytes)
#define OFF_G     0ull
#define SZ_G      ((size_t)3*P_*4)
#define OFF_Y2    (OFF_G + SZ_G)
#define SZ_Y      ((size_t)DIM*P_*4)          // 134,217,728
#define OFF_WT2   (OFF_Y2 + SZ_Y)
#define SZ_WT     ((size_t)DIM*DIM*4)         // 65,536
#define OFF_WT3   (OFF_WT2 + SZ_WT)
#define OFF_STATS (OFF_WT3 + SZ_WT)
#define N_STATS   4112
#define SZ_STATS  ((size_t)N_STATS*8)
#define OFF_AB    (OFF_STATS + SZ_STATS)
#define SZ_AB     4096ull
#define OFF_KPART (OFF_AB + SZ_AB)
#define NKBLK     2048                         // knn blocks (16 points each)
#define SZ_KPART  ((size_t)9*NKBLK*4)          // 73,728
#define OFF_Y3    (OFF_KPART + SZ_KPART)
#define NEED_A    (OFF_Y3 + SZ_Y)

// stats (f64) indices (conv layers only)
#define I_S2   16    // layer2: 8 banks x (128 sum + 128 sumsq)
#define I_S3   (16 + 8*256)
#define NBANK  8

// ab (float) layout
#define AB_W1F 0     // 128 x float4 folded W1 (a*w0,a*w1,a*w2,a*b1+beta)
#define AB_A2  512
#define AB_E2  640
#define AB_A3  768
#define AB_E3  896

__device__ __forceinline__ void atomAddD(double* p, double v) {
    __hip_atomic_fetch_add(p, v, __ATOMIC_RELAXED, __HIP_MEMORY_SCOPE_AGENT);
}

// ---------------------------------------------------------------------------
__global__ void zero_stats_kernel(double* __restrict__ st) {
    for (int i = threadIdx.x; i < N_STATS; i += 256) st[i] = 0.0;
}

// ---------------------------------------------------------------------------
// W transpose: Wt[c][d] = W[d][c] for W2 and W3 (each 128x128).
__global__ __launch_bounds__(256) void transposeW_kernel(
    const float* __restrict__ W2, const float* __restrict__ W3,
    float* __restrict__ Wt2, float* __restrict__ Wt3)
{
    const int idx = blockIdx.x * 256 + threadIdx.x;   // 0..32767
    const int which = idx >> 14;
    const int r = idx & 16383;
    const int c = r >> 7, d = r & 127;
    const float* src = which ? W3 : W2;
    float* dst = which ? Wt3 : Wt2;
    dst[c*DIM + d] = src[d*DIM + c];
}

// ---------------------------------------------------------------------------
// kNN + grouped offsets + layer-1 moment partials.
// Block = 1024 threads = 16 waves = 16 points; wave = one point.
// LDS point data in 4 b32 planes (conflict-free stride-1 reads).
// Distance arithmetic bit-identical to rounds 1-4.
__global__ __launch_bounds__(1024) void knn_group_kernel(
    const float* __restrict__ x, float* __restrict__ g, float* __restrict__ kpart)
{
    __shared__ float xsx[N_], xsy[N_], xsz[N_], xsq[N_];   // 32 KB
    __shared__ float listD[16][CAP];                       // 8 KB
    __shared__ int   listI[16][CAP];                       // 8 KB
    __shared__ float spart[16][12];
    const int b   = blockIdx.y;
    const int tid = threadIdx.x;
    const int wv  = tid >> 6;        // wave = local point 0..15
    const int ln  = tid & 63;
    const int n   = blockIdx.x * 16 + wv;
    const float* xb = x + (size_t)b * 3 * N_;

    for (int i = tid; i < N_; i += 1024) {
        const float a0 = xb[i], a1 = xb[N_ + i], a2 = xb[2*N_ + i];
        const float sq = __fadd_rn(__fadd_rn(__fmul_rn(a0,a0), __fmul_rn(a1,a1)), __fmul_rn(a2,a2));
        xsx[i] = a0; xsy[i] = a1; xsz[i] = a2; xsq[i] = sq;
    }
    __syncthreads();

    const float xn0 = xsx[n], xn1 = xsy[n], xn2 = xsz[n], sqn = xsq[n];

    // ---- Pass A: distances in registers + lane min
    float dreg[32];
    float lmin = INFINITY;
    #pragma unroll
    for (int i = 0; i < 32; ++i) {
        const int m = ln + 64*i;
        const float qx = xsx[m], qy = xsy[m], qz = xsz[m], qw = xsq[m];
        dreg[i] = __fadd_rn(__fmaf_rn(-2.f, __fmaf_rn(xn2, qz, __fmaf_rn(xn1, qy, __fmul_rn(xn0, qx))), sqn), qw);
        lmin = fminf(lmin, dreg[i]);
    }

    // ---- bound B = 8th smallest of the 64 lane minima
    float t = lmin, B = lmin;
    #pragma unroll
    for (int s = 0; s < 8; ++s) {
        float cur = t;
        #pragma unroll
        for (int m = 1; m < 64; m <<= 1) cur = fminf(cur, __shfl_xor(cur, m));
        B = cur;
        t = (t == cur) ? INFINITY : t;
    }

    // ---- Pass B: ballot-compact candidates with d <= B
    unsigned base = 0;
    #pragma unroll
    for (int i = 0; i < 32; ++i) {
        const bool pred = (dreg[i] <= B);
        const unsigned long long mk = __ballot(pred);
        if (pred) {
            const unsigned pos = base + (unsigned)__popcll(mk & ((1ull << ln) - 1ull));
            if (pos < CAP) { listD[wv][pos] = dreg[i]; listI[wv][pos] = ln + 64*i; }
        }
        base += (unsigned)__popcll(mk);
    }
    const int cnt = (base < CAP) ? (int)base : CAP;

    // ---- Pass C: 8x wave lex-argmin over compacted list (exact top_k)
    float cd0 = (ln < cnt)      ? listD[wv][ln]      : INFINITY;
    int   ci0 = (ln < cnt)      ? listI[wv][ln]      : 0x7FFFFFFF;
    float cd1 = (ln + 64 < cnt) ? listD[wv][ln + 64] : INFINITY;
    int   ci1 = (ln + 64 < cnt) ? listI[wv][ln + 64] : 0x7FFFFFFF;
    int myi = 0;
    #pragma unroll
    for (int sel = 0; sel < 8; ++sel) {
        const bool sw = (cd1 < cd0) || (cd1 == cd0 && ci1 < ci0);
        float pd = sw ? cd1 : cd0;
        int   pi = sw ? ci1 : ci0;
        #pragma unroll
        for (int m = 1; m < 64; m <<= 1) {
            const float od = __shfl_xor(pd, m);
            const int   oi = __shfl_xor(pi, m);
            if ((od < pd) || (od == pd && oi < pi)) { pd = od; pi = oi; }
        }
        myi = (ln == sel) ? pi : myi;
        if (ci0 == pi) cd0 = INFINITY;
        if (ci1 == pi) cd1 = INFINITY;
    }

    // ---- gather, g-write, stats (lanes 0..7 hold neighbors 0..7)
    if (ln < 8) {
        const float g0  = xsx[myi] - xn0;
        const float g1v = xsy[myi] - xn1;
        const float g2v = xsz[myi] - xn2;
        const size_t basep = ((size_t)b*N_ + n) * KNN;
        g[0*P_ + basep + ln] = g0;
        g[1*P_ + basep + ln] = g1v;
        g[2*P_ + basep + ln] = g2v;
        float s0 = g0, s1 = g1v, s2 = g2v;
        float s00 = g0*g0, s01 = g0*g1v, s02 = g0*g2v;
        float s11 = g1v*g1v, s12 = g1v*g2v, s22 = g2v*g2v;
        #pragma unroll
        for (int m = 1; m < 8; m <<= 1) {
            s0 += __shfl_xor(s0, m);  s1 += __shfl_xor(s1, m);  s2 += __shfl_xor(s2, m);
            s00 += __shfl_xor(s00, m); s01 += __shfl_xor(s01, m); s02 += __shfl_xor(s02, m);
            s11 += __shfl_xor(s11, m); s12 += __shfl_xor(s12, m); s22 += __shfl_xor(s22, m);
        }
        if (ln == 0) {
            spart[wv][0] = s0;  spart[wv][1] = s1;  spart[wv][2] = s2;
            spart[wv][3] = s00; spart[wv][4] = s01; spart[wv][5] = s02;
            spart[wv][6] = s11; spart[wv][7] = s12; spart[wv][8] = s22;
        }
    }
    __syncthreads();
    if (tid < 9) {
        float a = 0.f;
        #pragma unroll
        for (int w = 0; w < 16; ++w) a += spart[w][tid];
        kpart[tid*NKBLK + blockIdx.y*128 + blockIdx.x] = a;
    }
}

// ---------------------------------------------------------------------------
// Layer-1 BN stats from g moment partials; emit folded W1f.
__global__ __launch_bounds__(128) void finalize1_kernel(
    const float* __restrict__ kpart, const float* __restrict__ W1,
    const float* __restrict__ b1, const float* __restrict__ g1,
    const float* __restrict__ be1, float* __restrict__ ab)
{
    __shared__ double red[128];
    __shared__ double S9[9];
    const int tid = threadIdx.x;
    for (int m = 0; m < 9; ++m) {
        double a = 0.0;
        for (int i = tid; i < NKBLK; i += 128) a += (double)kpart[m*NKBLK + i];
        red[tid] = a;
        __syncthreads();
        if (tid == 0) {
            double s = 0.0;
            for (int j = 0; j < 128; ++j) s += red[j];
            S9[m] = s;
        }
        __syncthreads();
    }
    const int d = tid;
    const double inv = 1.0 / (double)P_;
    const double mu0 = S9[0]*inv, mu1 = S9[1]*inv, mu2 = S9[2]*inv;
    const double c00 = S9[3]*inv - mu0*mu0;
    const double c01 = S9[4]*inv - mu0*mu1;
    const double c02 = S9[5]*inv - mu0*mu2;
    const double c11 = S9[6]*inv - mu1*mu1;
    const double c12 = S9[7]*inv - mu1*mu2;
    const double c22 = S9[8]*inv - mu2*mu2;
    const double w0 = W1[d*3+0], w1 = W1[d*3+1], w2 = W1[d*3+2];
    const double mean = w0*mu0 + w1*mu1 + w2*mu2 + (double)b1[d];
    double var = w0*w0*c00 + w1*w1*c11 + w2*w2*c22
               + 2.0*(w0*w1*c01 + w0*w2*c02 + w1*w2*c12);
    if (var < 0.0) var = 0.0;
    const double r = 1.0 / sqrt(var + 1e-5);
    const double alpha = (double)g1[d] * r;
    const double beta  = (double)be1[d] - mean*alpha;
    ab[AB_W1F + 4*d + 0] = (float)(alpha * w0);
    ab[AB_W1F + 4*d + 1] = (float)(alpha * w1);
    ab[AB_W1F + 4*d + 2] = (float)(alpha * w2);
    ab[AB_W1F + 4*d + 3] = (float)(alpha * (double)b1[d] + beta);
}

// Layers 2/3: reduce banked sums -> folded affine alpha/beta.
__global__ void finalize23_kernel(
    const double* __restrict__ st, int soff,
    const float* __restrict__ gg, const float* __restrict__ bee,
    float* __restrict__ ab, int aoff)
{
    const int d = threadIdx.x;
    if (d >= DIM) return;
    double s1 = 0.0, s2 = 0.0;
    #pragma unroll
    for (int k = 0; k < NBANK; ++k) {
        s1 += st[soff + k*256 + d];
        s2 += st[soff + k*256 + 128 + d];
    }
    const double inv = 1.0 / (double)P_;
    const double mean = s1 * inv;
    double var = s2 * inv - mean*mean;
    if (var < 0.0) var = 0.0;
    const double r = 1.0 / sqrt(var + 1e-5);
    const double alpha = (double)gg[d] * r;
    ab[aoff + d]       = (float)alpha;
    ab[aoff + 128 + d] = (float)((double)bee[d] - mean*alpha);
}

// ---------------------------------------------------------------------------
// conv GEMM: block = 128p tile, 4 waves; wave w owns d in [32w,32w+32),
// lane ln owns p in {ln, ln+64}. W via wave-uniform scalar loads from Wt[c][d];
// H staged in LDS per 32-c chunk (conflict-free b32 columns).
// SRC 0: H from g via folded W1f (conv2).  SRC 1: H = relu(a2*y2+e2) (conv3).
// MODE 0: store Y + stats.  MODE 1: stats only.  MODE 2: fused BN3+ReLU+max_k.
template<int SRC, int MODE>
__global__ __launch_bounds__(256) void conv_kernel(
    const float* __restrict__ Hsrc, const float* __restrict__ Wt,
    const float* __restrict__ ab,   const float* __restrict__ bias,
    float* __restrict__ Y, float* __restrict__ out,
    double* __restrict__ stats, int statoff)
{
    __shared__ float Hs[32*128];     // 16 KB
    const int tid = threadIdx.x;
    const int p0g = blockIdx.x * 128;
    const int ln  = tid & 63;
    const int dbase = __builtin_amdgcn_readfirstlane(32 * (tid >> 6));

    // staging: thread t covers column scol for rows srow0, srow0+2, ...
    const int scol  = tid & 127;
    const int srow0 = tid >> 7;      // wave-uniform (0 for waves 0-1, 1 for 2-3)

    float gx, gy, gz;
    if constexpr (SRC == 0) {
        gx = Hsrc[0*P_ + p0g + scol];
        gy = Hsrc[1*P_ + p0g + scol];
        gz = Hsrc[2*P_ + p0g + scol];
    }

    float acc[32][2];
    #pragma unroll
    for (int j = 0; j < 32; ++j) { acc[j][0] = 0.f; acc[j][1] = 0.f; }

    for (int chunk = 0; chunk < 4; ++chunk) {
        const int c0 = chunk * 32;
        __syncthreads();             // previous chunk's reads done
        if constexpr (SRC == 0) {
            #pragma unroll
            for (int it = 0; it < 16; ++it) {
                const int r = srow0 + 2*it;
                const float4 wf = *(const float4*)&ab[AB_W1F + 4*(c0 + r)];
                Hs[r*128 + scol] =
                    fmaxf(__fmaf_rn(wf.x, gx, __fmaf_rn(wf.y, gy, __fmaf_rn(wf.z, gz, wf.w))), 0.f);
            }
        } else {
            #pragma unroll
            for (int it = 0; it < 16; ++it) {
                const int r = srow0 + 2*it;
                const int c = c0 + r;
                const float v = Hsrc[(size_t)c*P_ + p0g + scol];
                Hs[r*128 + scol] = fmaxf(__fmaf_rn(ab[AB_A2 + c], v, ab[AB_E2 + c]), 0.f);
            }
        }
        __syncthreads();

        #pragma unroll 4
        for (int cc = 0; cc < 32; ++cc) {
            const float h0 = Hs[cc*128 + ln];
            const float h1 = Hs[cc*128 + 64 + ln];
            const float* wr = Wt + (size_t)(c0 + cc)*DIM + dbase;   // wave-uniform
            #pragma unroll
            for (int q = 0; q < 8; ++q) {
                const float4 w4 = *(const float4*)&wr[q*4];
                acc[q*4+0][0] = __fmaf_rn(w4.x, h0, acc[q*4+0][0]);
                acc[q*4+0][1] = __fmaf_rn(w4.x, h1, acc[q*4+0][1]);
                acc[q*4+1][0] = __fmaf_rn(w4.y, h0, acc[q*4+1][0]);
                acc[q*4+1][1] = __fmaf_rn(w4.y, h1, acc[q*4+1][1]);
                acc[q*4+2][0] = __fmaf_rn(w4.z, h0, acc[q*4+2][0]);
                acc[q*4+2][1] = __fmaf_rn(w4.z, h1, acc[q*4+2][1]);
                acc[q*4+3][0] = __fmaf_rn(w4.w, h0, acc[q*4+3][0]);
                acc[q*4+3][1] = __fmaf_rn(w4.w, h1, acc[q*4+3][1]);
            }
        }
    }

    if constexpr (MODE == 2) {
        #pragma unroll
        for (int j = 0; j < 32; ++j) {
            const int d = dbase + j;
            const float bb = bias[d];
            const float a = ab[AB_A3 + d], e = ab[AB_E3 + d];
            float m0 = __fmaf_rn(a, acc[j][0] + bb, e);
            float m1 = __fmaf_rn(a, acc[j][1] + bb, e);
            m0 = fmaxf(m0, __shfl_xor(m0, 1));
            m0 = fmaxf(m0, __shfl_xor(m0, 2));
            m0 = fmaxf(m0, __shfl_xor(m0, 4));
            m1 = fmaxf(m1, __shfl_xor(m1, 1));
            m1 = fmaxf(m1, __shfl_xor(m1, 2));
            m1 = fmaxf(m1, __shfl_xor(m1, 4));
            if ((ln & 7) == 0) {
                const int q = ln >> 3;
                int pt = (p0g >> 3) + q;
                out[((size_t)(pt >> 11)*DIM + d)*N_ + (pt & (N_-1))] = fmaxf(m0, 0.f);
                pt += 8;
                out[((size_t)(pt >> 11)*DIM + d)*N_ + (pt & (N_-1))] = fmaxf(m1, 0.f);
            }
        }
    } else {
        const int bank = blockIdx.x & (NBANK-1);
        #pragma unroll
        for (int j = 0; j < 32; ++j) {
            const int d = dbase + j;
            const float bb = bias[d];
            const float v0 = acc[j][0] + bb;
            const float v1 = acc[j][1] + bb;
            if constexpr (MODE == 0) {
                Y[(size_t)d*P_ + p0g + ln]      = v0;
                Y[(size_t)d*P_ + p0g + 64 + ln] = v1;
            }
            float s1 = v0 + v1;
            float s2 = __fmaf_rn(v0, v0, v1*v1);
            #pragma unroll
            for (int m = 1; m < 64; m <<= 1) { s1 += __shfl_xor(s1, m); s2 += __shfl_xor(s2, m); }
            if (ln == 0) {
                atomAddD(&stats[statoff + bank*256 + d], (double)s1);
                atomAddD(&stats[statoff + bank*256 + 128 + d], (double)s2);
            }
        }
    }
}

// ---------------------------------------------------------------------------
// Variant A epilogue: out[b,d,n] = max_kk relu(a3*y3 + e3)
__global__ __launch_bounds__(256) void out_kernel(
    const float* __restrict__ y3, const float* __restrict__ ab, float* __restrict__ out)
{
    const size_t idx = (size_t)blockIdx.x*256 + threadIdx.x;   // over B*DIM*N
    const int n = (int)(idx & (N_-1));
    const int d = (int)((idx >> 11) & (DIM-1));
    const int b = (int)(idx >> 18);
    const float a = ab[AB_A3 + d], e = ab[AB_E3 + d];
    const size_t base = (size_t)d*P_ + ((size_t)b*N_ + n)*KNN;
    const float4 v0 = *(const float4*)&y3[base];
    const float4 v1 = *(const float4*)&y3[base + 4];
    float m = __fmaf_rn(a, v0.x, e);
    m = fmaxf(m, __fmaf_rn(a, v0.y, e));
    m = fmaxf(m, __fmaf_rn(a, v0.z, e));
    m = fmaxf(m, __fmaf_rn(a, v0.w, e));
    m = fmaxf(m, __fmaf_rn(a, v1.x, e));
    m = fmaxf(m, __fmaf_rn(a, v1.y, e));
    m = fmaxf(m, __fmaf_rn(a, v1.z, e));
    m = fmaxf(m, __fmaf_rn(a, v1.w, e));
    out[idx] = fmaxf(m, 0.f);
}

// ---------------------------------------------------------------------------
extern "C" void kernel_launch(void* const* d_in, const int* in_sizes, int n_in,
                              void* d_out, int out_size, void* d_ws, size_t ws_size,
                              hipStream_t stream) {
    (void)in_sizes; (void)n_in; (void)out_size;
    const float* x   = (const float*)d_in[0];
    const float* W1  = (const float*)d_in[1];
    const float* b1  = (const float*)d_in[2];
    const float* g1  = (const float*)d_in[3];
    const float* be1 = (const float*)d_in[4];
    const float* W2  = (const float*)d_in[5];
    const float* b2  = (const float*)d_in[6];
    const float* g2  = (const float*)d_in[7];
    const float* be2 = (const float*)d_in[8];
    const float* W3  = (const float*)d_in[9];
    const float* b3  = (const float*)d_in[10];
    const float* g3  = (const float*)d_in[11];
    const float* be3 = (const float*)d_in[12];

    float*  out = (float*)d_out;
    char*   ws  = (char*)d_ws;
    float*  g   = (float*)(ws + OFF_G);
    float*  y2  = (float*)(ws + OFF_Y2);
    float*  wt2 = (float*)(ws + OFF_WT2);
    float*  wt3 = (float*)(ws + OFF_WT3);
    double* st  = (double*)(ws + OFF_STATS);
    float*  ab  = (float*)(ws + OFF_AB);
    float*  kp  = (float*)(ws + OFF_KPART);
    float*  y3  = (float*)(ws + OFF_Y3);

    const bool useA = (ws_size >= NEED_A);

    zero_stats_kernel<<<1, 256, 0, stream>>>(st);
    transposeW_kernel<<<128, 256, 0, stream>>>(W2, W3, wt2, wt3);
    knn_group_kernel<<<dim3(128, B_), 1024, 0, stream>>>(x, g, kp);
    finalize1_kernel<<<1, 128, 0, stream>>>(kp, W1, b1, g1, be1, ab);
    conv_kernel<0,0><<<P_/128, 256, 0, stream>>>(g, wt2, ab, b2, y2, nullptr, st, I_S2);
    finalize23_kernel<<<1, 128, 0, stream>>>(st, I_S2, g2, be2, ab, AB_A2);
    if (useA) {
        conv_kernel<1,0><<<P_/128, 256, 0, stream>>>(y2, wt3, ab, b3, y3, nullptr, st, I_S3);
        finalize23_kernel<<<1, 128, 0, stream>>>(st, I_S3, g3, be3, ab, AB_A3);
        out_kernel<<<(B_*DIM*N_)/256, 256, 0, stream>>>(y3, ab, out);
    } else {
        conv_kernel<1,1><<<P_/128, 256, 0, stream>>>(y2, wt3, ab, b3, nullptr, nullptr, st, I_S3);
        finalize23_kernel<<<1, 128, 0, stream>>>(st, I_S3, g3, be3, ab, AB_A3);
        conv_kernel<1,2><<<P_/128, 256, 0, stream>>>(y2, wt3, ab, b3, nullptr, out, st, I_S3);
    }
}

// Round 6
// 378.266 us; speedup vs baseline: 1.6469x; 1.6469x over previous
//
#include <hip/hip_runtime.h>
#include <hip/hip_bf16.h>
#include <math.h>

// ---------------------------------------------------------------------------
// FeatureNet (DGCNN edge-conv block), MI355X / gfx950, f32, round 6.
//
// Round-6 changes:
//  * conv hot loop reverted to the proven round-4 structure (round-5
//    scalar-pipe restructure regressed: FETCH 2.4->66MB, latency-bound).
//  * conv3 single pass: computes BN3 stats + per-point max_k/min_k of raw y3,
//    stores minmax in-place into the consumed y2 block (no extra ws).
//    BN3+ReLU+max applied by tiny bn3max epilogue using sign of alpha3
//    (max_k relu(a*y+e) = relu(a*max/min+e) by monotonicity).
// ---------------------------------------------------------------------------

#define B_   16
#define N_   2048
#define KNN  8
#define DIM  128
#define P_   (B_*N_*KNN)   // 262144
#define CAP  128           // compacted candidate capacity per point

// ws layout (bytes)
#define OFF_G     0ull
#define SZ_G      ((size_t)3*P_*4)
#define OFF_Y2    (OFF_G + SZ_G)
#define SZ_Y      ((size_t)DIM*P_*4)          // 134,217,728
#define OFF_WT2   (OFF_Y2 + SZ_Y)
#define SZ_WT     ((size_t)DIM*DIM*4)         // 65,536
#define OFF_WT3   (OFF_WT2 + SZ_WT)
#define OFF_STATS (OFF_WT3 + SZ_WT)
#define N_STATS   4112
#define SZ_STATS  ((size_t)N_STATS*8)
#define OFF_AB    (OFF_STATS + SZ_STATS)
#define SZ_AB     4096ull
#define OFF_KPART (OFF_AB + SZ_AB)
#define NKBLK     2048                         // knn blocks (16 points each)
#define SZ_KPART  ((size_t)9*NKBLK*4)          // 73,728

// stats (f64) indices (conv layers only)
#define I_S2   16    // layer2: 8 banks x (128 sum + 128 sumsq)
#define I_S3   (16 + 8*256)
#define NBANK  8

// ab (float) layout
#define AB_W1F 0     // 128 x float4 folded W1 (a*w0,a*w1,a*w2,a*b1+beta)
#define AB_A2  512
#define AB_E2  640
#define AB_A3  768
#define AB_E3  896

__device__ __forceinline__ void atomAddD(double* p, double v) {
    __hip_atomic_fetch_add(p, v, __ATOMIC_RELAXED, __HIP_MEMORY_SCOPE_AGENT);
}

// ---------------------------------------------------------------------------
__global__ void zero_stats_kernel(double* __restrict__ st) {
    for (int i = threadIdx.x; i < N_STATS; i += 256) st[i] = 0.0;
}

// ---------------------------------------------------------------------------
// W transpose: Wt[c][d] = W[d][c] for W2 and W3 (each 128x128).
__global__ __launch_bounds__(256) void transposeW_kernel(
    const float* __restrict__ W2, const float* __restrict__ W3,
    float* __restrict__ Wt2, float* __restrict__ Wt3)
{
    const int idx = blockIdx.x * 256 + threadIdx.x;   // 0..32767
    const int which = idx >> 14;
    const int r = idx & 16383;
    const int c = r >> 7, d = r & 127;
    const float* src = which ? W3 : W2;
    float* dst = which ? Wt3 : Wt2;
    dst[c*DIM + d] = src[d*DIM + c];
}

// ---------------------------------------------------------------------------
// kNN + grouped offsets + layer-1 moment partials.
// Block = 1024 threads = 16 waves = 16 points; wave = one point.
// Pass A: per-lane distances in regs; B = 8th smallest of 64 lane minima.
// Pass B: ballot-compact d<=B into LDS. Pass C: 8x wave lex-argmin (d,idx)
// == exact lax.top_k selection. Distance arithmetic bit-identical to r1-5.
__global__ __launch_bounds__(1024) void knn_group_kernel(
    const float* __restrict__ x, float* __restrict__ g, float* __restrict__ kpart)
{
    __shared__ float xsx[N_], xsy[N_], xsz[N_], xsq[N_];   // 32 KB
    __shared__ float listD[16][CAP];                       // 8 KB
    __shared__ int   listI[16][CAP];                       // 8 KB
    __shared__ float spart[16][12];
    const int b   = blockIdx.y;
    const int tid = threadIdx.x;
    const int wv  = tid >> 6;        // wave = local point 0..15
    const int ln  = tid & 63;
    const int n   = blockIdx.x * 16 + wv;
    const float* xb = x + (size_t)b * 3 * N_;

    for (int i = tid; i < N_; i += 1024) {
        const float a0 = xb[i], a1 = xb[N_ + i], a2 = xb[2*N_ + i];
        const float sq = __fadd_rn(__fadd_rn(__fmul_rn(a0,a0), __fmul_rn(a1,a1)), __fmul_rn(a2,a2));
        xsx[i] = a0; xsy[i] = a1; xsz[i] = a2; xsq[i] = sq;
    }
    __syncthreads();

    const float xn0 = xsx[n], xn1 = xsy[n], xn2 = xsz[n], sqn = xsq[n];

    // ---- Pass A
    float dreg[32];
    float lmin = INFINITY;
    #pragma unroll
    for (int i = 0; i < 32; ++i) {
        const int m = ln + 64*i;
        const float qx = xsx[m], qy = xsy[m], qz = xsz[m], qw = xsq[m];
        dreg[i] = __fadd_rn(__fmaf_rn(-2.f, __fmaf_rn(xn2, qz, __fmaf_rn(xn1, qy, __fmul_rn(xn0, qx))), sqn), qw);
        lmin = fminf(lmin, dreg[i]);
    }

    // ---- bound B = 8th smallest of the 64 lane minima
    float t = lmin, B = lmin;
    #pragma unroll
    for (int s = 0; s < 8; ++s) {
        float cur = t;
        #pragma unroll
        for (int m = 1; m < 64; m <<= 1) cur = fminf(cur, __shfl_xor(cur, m));
        B = cur;
        t = (t == cur) ? INFINITY : t;
    }

    // ---- Pass B: ballot-compact candidates with d <= B
    unsigned base = 0;
    #pragma unroll
    for (int i = 0; i < 32; ++i) {
        const bool pred = (dreg[i] <= B);
        const unsigned long long mk = __ballot(pred);
        if (pred) {
            const unsigned pos = base + (unsigned)__popcll(mk & ((1ull << ln) - 1ull));
            if (pos < CAP) { listD[wv][pos] = dreg[i]; listI[wv][pos] = ln + 64*i; }
        }
        base += (unsigned)__popcll(mk);
    }
    const int cnt = (base < CAP) ? (int)base : CAP;

    // ---- Pass C: 8x wave lex-argmin over compacted list (exact top_k)
    float cd0 = (ln < cnt)      ? listD[wv][ln]      : INFINITY;
    int   ci0 = (ln < cnt)      ? listI[wv][ln]      : 0x7FFFFFFF;
    float cd1 = (ln + 64 < cnt) ? listD[wv][ln + 64] : INFINITY;
    int   ci1 = (ln + 64 < cnt) ? listI[wv][ln + 64] : 0x7FFFFFFF;
    int myi = 0;
    #pragma unroll
    for (int sel = 0; sel < 8; ++sel) {
        const bool sw = (cd1 < cd0) || (cd1 == cd0 && ci1 < ci0);
        float pd = sw ? cd1 : cd0;
        int   pi = sw ? ci1 : ci0;
        #pragma unroll
        for (int m = 1; m < 64; m <<= 1) {
            const float od = __shfl_xor(pd, m);
            const int   oi = __shfl_xor(pi, m);
            if ((od < pd) || (od == pd && oi < pi)) { pd = od; pi = oi; }
        }
        myi = (ln == sel) ? pi : myi;
        if (ci0 == pi) cd0 = INFINITY;
        if (ci1 == pi) cd1 = INFINITY;
    }

    // ---- gather, g-write, stats (lanes 0..7 hold neighbors 0..7)
    if (ln < 8) {
        const float g0  = xsx[myi] - xn0;
        const float g1v = xsy[myi] - xn1;
        const float g2v = xsz[myi] - xn2;
        const size_t basep = ((size_t)b*N_ + n) * KNN;
        g[0*P_ + basep + ln] = g0;
        g[1*P_ + basep + ln] = g1v;
        g[2*P_ + basep + ln] = g2v;
        float s0 = g0, s1 = g1v, s2 = g2v;
        float s00 = g0*g0, s01 = g0*g1v, s02 = g0*g2v;
        float s11 = g1v*g1v, s12 = g1v*g2v, s22 = g2v*g2v;
        #pragma unroll
        for (int m = 1; m < 8; m <<= 1) {
            s0 += __shfl_xor(s0, m);  s1 += __shfl_xor(s1, m);  s2 += __shfl_xor(s2, m);
            s00 += __shfl_xor(s00, m); s01 += __shfl_xor(s01, m); s02 += __shfl_xor(s02, m);
            s11 += __shfl_xor(s11, m); s12 += __shfl_xor(s12, m); s22 += __shfl_xor(s22, m);
        }
        if (ln == 0) {
            spart[wv][0] = s0;  spart[wv][1] = s1;  spart[wv][2] = s2;
            spart[wv][3] = s00; spart[wv][4] = s01; spart[wv][5] = s02;
            spart[wv][6] = s11; spart[wv][7] = s12; spart[wv][8] = s22;
        }
    }
    __syncthreads();
    if (tid < 9) {
        float a = 0.f;
        #pragma unroll
        for (int w = 0; w < 16; ++w) a += spart[w][tid];
        kpart[tid*NKBLK + blockIdx.y*128 + blockIdx.x] = a;
    }
}

// ---------------------------------------------------------------------------
// Layer-1 BN stats from g moment partials; emit folded W1f.
__global__ __launch_bounds__(128) void finalize1_kernel(
    const float* __restrict__ kpart, const float* __restrict__ W1,
    const float* __restrict__ b1, const float* __restrict__ g1,
    const float* __restrict__ be1, float* __restrict__ ab)
{
    __shared__ double red[128];
    __shared__ double S9[9];
    const int tid = threadIdx.x;
    for (int m = 0; m < 9; ++m) {
        double a = 0.0;
        for (int i = tid; i < NKBLK; i += 128) a += (double)kpart[m*NKBLK + i];
        red[tid] = a;
        __syncthreads();
        if (tid == 0) {
            double s = 0.0;
            for (int j = 0; j < 128; ++j) s += red[j];
            S9[m] = s;
        }
        __syncthreads();
    }
    const int d = tid;
    const double inv = 1.0 / (double)P_;
    const double mu0 = S9[0]*inv, mu1 = S9[1]*inv, mu2 = S9[2]*inv;
    const double c00 = S9[3]*inv - mu0*mu0;
    const double c01 = S9[4]*inv - mu0*mu1;
    const double c02 = S9[5]*inv - mu0*mu2;
    const double c11 = S9[6]*inv - mu1*mu1;
    const double c12 = S9[7]*inv - mu1*mu2;
    const double c22 = S9[8]*inv - mu2*mu2;
    const double w0 = W1[d*3+0], w1 = W1[d*3+1], w2 = W1[d*3+2];
    const double mean = w0*mu0 + w1*mu1 + w2*mu2 + (double)b1[d];
    double var = w0*w0*c00 + w1*w1*c11 + w2*w2*c22
               + 2.0*(w0*w1*c01 + w0*w2*c02 + w1*w2*c12);
    if (var < 0.0) var = 0.0;
    const double r = 1.0 / sqrt(var + 1e-5);
    const double alpha = (double)g1[d] * r;
    const double beta  = (double)be1[d] - mean*alpha;
    ab[AB_W1F + 4*d + 0] = (float)(alpha * w0);
    ab[AB_W1F + 4*d + 1] = (float)(alpha * w1);
    ab[AB_W1F + 4*d + 2] = (float)(alpha * w2);
    ab[AB_W1F + 4*d + 3] = (float)(alpha * (double)b1[d] + beta);
}

// Layers 2/3: reduce banked sums -> folded affine alpha/beta.
__global__ void finalize23_kernel(
    const double* __restrict__ st, int soff,
    const float* __restrict__ gg, const float* __restrict__ bee,
    float* __restrict__ ab, int aoff)
{
    const int d = threadIdx.x;
    if (d >= DIM) return;
    double s1 = 0.0, s2 = 0.0;
    #pragma unroll
    for (int k = 0; k < NBANK; ++k) {
        s1 += st[soff + k*256 + d];
        s2 += st[soff + k*256 + 128 + d];
    }
    const double inv = 1.0 / (double)P_;
    const double mean = s1 * inv;
    double var = s2 * inv - mean*mean;
    if (var < 0.0) var = 0.0;
    const double r = 1.0 / sqrt(var + 1e-5);
    const double alpha = (double)gg[d] * r;
    ab[aoff + d]       = (float)alpha;
    ab[aoff + 128 + d] = (float)((double)bee[d] - mean*alpha);
}

// ---------------------------------------------------------------------------
// conv GEMM (round-4 proven structure): C[128d][128p] = Wt^T x H, H per 32-c
// chunk in LDS. Block 256 thr: tx=p (16x4+4), ty=d (16x8). 8d x 8p / thread.
// SRC 0: H from g via folded W1f (conv2).  SRC 1: H = relu(a2*y2+e2) (conv3).
// MODE 0: store Y + stats.
// MODE 3: stats + per-point max_k/min_k of raw y written in-place into the
//         consumed Y(=Hsrc) block: slots [0..15]=max, [16..31]=min per
//         (d, point-block). Safe: this block alone owns that p-range and all
//         its staging reads completed before the epilogue.
// NOTE: Hsrc/Y intentionally NOT __restrict__ (they alias in MODE 3).
template<int SRC, int MODE>
__global__ __launch_bounds__(256) void conv_kernel(
    const float* Hsrc, const float* __restrict__ Wt,
    const float* __restrict__ ab,   const float* __restrict__ bias,
    float* Y, double* __restrict__ stats, int statoff)
{
    __shared__ __align__(16) float Hs[32*128];
    __shared__ __align__(16) float Ws[32*128];
    const int tid = threadIdx.x;
    const int p0g = blockIdx.x * 128;

    const int tx = tid & 15, ty = tid >> 4;
    const int p0 = tx*4, d0 = ty*8;
    const int pq = (tid & 31) * 4;   // staging column (p or d)
    const int cg = tid >> 5;         // staging row group 0..7

    float4 g0q, g1q, g2q;
    if constexpr (SRC == 0) {
        g0q = *(const float4*)&Hsrc[0*P_ + p0g + pq];
        g1q = *(const float4*)&Hsrc[1*P_ + p0g + pq];
        g2q = *(const float4*)&Hsrc[2*P_ + p0g + pq];
    }

    float acc[8][8];
    #pragma unroll
    for (int i = 0; i < 8; ++i)
        #pragma unroll
        for (int j = 0; j < 8; ++j) acc[i][j] = 0.f;

    for (int chunk = 0; chunk < 4; ++chunk) {
        const int c0 = chunk * 32;
        __syncthreads();
        if constexpr (SRC == 0) {
            #pragma unroll
            for (int it = 0; it < 4; ++it) {
                const int cr = cg + 8*it;
                const float4 wf = *(const float4*)&ab[AB_W1F + 4*(c0 + cr)];
                float4 h;
                h.x = fmaxf(__fmaf_rn(wf.x, g0q.x, __fmaf_rn(wf.y, g1q.x, __fmaf_rn(wf.z, g2q.x, wf.w))), 0.f);
                h.y = fmaxf(__fmaf_rn(wf.x, g0q.y, __fmaf_rn(wf.y, g1q.y, __fmaf_rn(wf.z, g2q.y, wf.w))), 0.f);
                h.z = fmaxf(__fmaf_rn(wf.x, g0q.z, __fmaf_rn(wf.y, g1q.z, __fmaf_rn(wf.z, g2q.z, wf.w))), 0.f);
                h.w = fmaxf(__fmaf_rn(wf.x, g0q.w, __fmaf_rn(wf.y, g1q.w, __fmaf_rn(wf.z, g2q.w, wf.w))), 0.f);
                *(float4*)&Hs[cr*128 + pq] = h;
            }
        } else {
            #pragma unroll
            for (int it = 0; it < 4; ++it) {
                const int cr = cg + 8*it;
                const int c = c0 + cr;
                const float4 v = *(const float4*)&Hsrc[(size_t)c*P_ + p0g + pq];
                const float a = ab[AB_A2 + c], e = ab[AB_E2 + c];
                float4 h;
                h.x = fmaxf(__fmaf_rn(a, v.x, e), 0.f);
                h.y = fmaxf(__fmaf_rn(a, v.y, e), 0.f);
                h.z = fmaxf(__fmaf_rn(a, v.z, e), 0.f);
                h.w = fmaxf(__fmaf_rn(a, v.w, e), 0.f);
                *(float4*)&Hs[cr*128 + pq] = h;
            }
        }
        #pragma unroll
        for (int it = 0; it < 4; ++it) {
            const int cr = cg + 8*it;
            *(float4*)&Ws[cr*128 + pq] = *(const float4*)&Wt[(size_t)(c0 + cr)*DIM + pq];
        }
        __syncthreads();

        #pragma unroll 4
        for (int cc = 0; cc < 32; ++cc) {
            const float4 h0 = *(const float4*)&Hs[cc*128 + p0];
            const float4 h1 = *(const float4*)&Hs[cc*128 + 64 + p0];
            const float4 w0 = *(const float4*)&Ws[cc*128 + d0];
            const float4 w1 = *(const float4*)&Ws[cc*128 + d0 + 4];
            const float wr[8] = {w0.x,w0.y,w0.z,w0.w,w1.x,w1.y,w1.z,w1.w};
            const float hr[8] = {h0.x,h0.y,h0.z,h0.w,h1.x,h1.y,h1.z,h1.w};
            #pragma unroll
            for (int i = 0; i < 8; ++i)
                #pragma unroll
                for (int j = 0; j < 8; ++j)
                    acc[i][j] = __fmaf_rn(wr[i], hr[j], acc[i][j]);
        }
    }

    const int bank = blockIdx.x & (NBANK-1);
    #pragma unroll
    for (int i = 0; i < 8; ++i) {
        const int d = d0 + i;
        const float bb = bias[d];
        float v[8];
        #pragma unroll
        for (int j = 0; j < 8; ++j) v[j] = acc[i][j] + bb;
        if constexpr (MODE == 0) {
            float4 o0; o0.x=v[0]; o0.y=v[1]; o0.z=v[2]; o0.w=v[3];
            float4 o1; o1.x=v[4]; o1.y=v[5]; o1.z=v[6]; o1.w=v[7];
            *(float4*)&Y[(size_t)d*P_ + p0g + p0]      = o0;
            *(float4*)&Y[(size_t)d*P_ + p0g + 64 + p0] = o1;
        }
        // stats (both modes)
        float s1 = ((v[0]+v[1])+(v[2]+v[3])) + ((v[4]+v[5])+(v[6]+v[7]));
        float s2 = ((v[0]*v[0]+v[1]*v[1])+(v[2]*v[2]+v[3]*v[3]))
                 + ((v[4]*v[4]+v[5]*v[5])+(v[6]*v[6]+v[7]*v[7]));
        #pragma unroll
        for (int m = 1; m < 16; m <<= 1) { s1 += __shfl_xor(s1, m); s2 += __shfl_xor(s2, m); }
        if ((tid & 15) == 0) {
            atomAddD(&stats[statoff + bank*256 + d], s1);
            atomAddD(&stats[statoff + bank*256 + 128 + d], s2);
        }
        if constexpr (MODE == 3) {
            // min/max over k: 8 consecutive p = lanes tid and tid^1 (4 each)
            float mx0 = fmaxf(fmaxf(v[0],v[1]), fmaxf(v[2],v[3]));
            float mn0 = fminf(fminf(v[0],v[1]), fminf(v[2],v[3]));
            float mx1 = fmaxf(fmaxf(v[4],v[5]), fmaxf(v[6],v[7]));
            float mn1 = fminf(fminf(v[4],v[5]), fminf(v[6],v[7]));
            mx0 = fmaxf(mx0, __shfl_xor(mx0, 1)); mn0 = fminf(mn0, __shfl_xor(mn0, 1));
            mx1 = fmaxf(mx1, __shfl_xor(mx1, 1)); mn1 = fminf(mn1, __shfl_xor(mn1, 1));
            if ((tid & 1) == 0) {
                const int s = tx >> 1;                 // point-in-block 0..7
                float* yb = Y + (size_t)d*P_ + p0g;
                yb[s]      = mx0;      // point s      (max)
                yb[8 + s]  = mx1;      // point s+8    (max)
                yb[16 + s] = mn0;      // point s      (min)
                yb[24 + s] = mn1;      // point s+8    (min)
            }
        }
    }
}

// ---------------------------------------------------------------------------
// Epilogue: out[b,d,n] = relu(a3*(a3>=0 ? max_k : min_k) + e3)
__global__ __launch_bounds__(256) void bn3max_kernel(
    const float* __restrict__ ymm, const float* __restrict__ ab, float* __restrict__ out)
{
    const int idx = blockIdx.x*256 + threadIdx.x;   // over B*DIM*N = 4194304
    const int n = idx & (N_-1);
    const int d = (idx >> 11) & (DIM-1);
    const int b = idx >> 18;
    const int pt  = b*N_ + n;
    const int blk = pt >> 4;
    const int j   = pt & 15;
    const size_t base = (size_t)d*P_ + (size_t)blk*128;
    const float a = ab[AB_A3 + d], e = ab[AB_E3 + d];
    const float mx = ymm[base + j];
    const float mn = ymm[base + 16 + j];
    const float v = (a >= 0.f) ? mx : mn;
    out[idx] = fmaxf(__fmaf_rn(a, v, e), 0.f);
}

// ---------------------------------------------------------------------------
extern "C" void kernel_launch(void* const* d_in, const int* in_sizes, int n_in,
                              void* d_out, int out_size, void* d_ws, size_t ws_size,
                              hipStream_t stream) {
    (void)in_sizes; (void)n_in; (void)out_size; (void)ws_size;
    const float* x   = (const float*)d_in[0];
    const float* W1  = (const float*)d_in[1];
    const float* b1  = (const float*)d_in[2];
    const float* g1  = (const float*)d_in[3];
    const float* be1 = (const float*)d_in[4];
    const float* W2  = (const float*)d_in[5];
    const float* b2  = (const float*)d_in[6];
    const float* g2  = (const float*)d_in[7];
    const float* be2 = (const float*)d_in[8];
    const float* W3  = (const float*)d_in[9];
    const float* b3  = (const float*)d_in[10];
    const float* g3  = (const float*)d_in[11];
    const float* be3 = (const float*)d_in[12];

    float*  out = (float*)d_out;
    char*   ws  = (char*)d_ws;
    float*  g   = (float*)(ws + OFF_G);
    float*  y2  = (float*)(ws + OFF_Y2);
    float*  wt2 = (float*)(ws + OFF_WT2);
    float*  wt3 = (float*)(ws + OFF_WT3);
    double* st  = (double*)(ws + OFF_STATS);
    float*  ab  = (float*)(ws + OFF_AB);
    float*  kp  = (float*)(ws + OFF_KPART);

    zero_stats_kernel<<<1, 256, 0, stream>>>(st);
    transposeW_kernel<<<128, 256, 0, stream>>>(W2, W3, wt2, wt3);
    knn_group_kernel<<<dim3(128, B_), 1024, 0, stream>>>(x, g, kp);
    finalize1_kernel<<<1, 128, 0, stream>>>(kp, W1, b1, g1, be1, ab);
    conv_kernel<0,0><<<P_/128, 256, 0, stream>>>(g, wt2, ab, b2, y2, st, I_S2);
    finalize23_kernel<<<1, 128, 0, stream>>>(st, I_S2, g2, be2, ab, AB_A2);
    conv_kernel<1,3><<<P_/128, 256, 0, stream>>>(y2, wt3, ab, b3, y2, st, I_S3);
    finalize23_kernel<<<1, 128, 0, stream>>>(st, I_S3, g3, be3, ab, AB_A3);
    bn3max_kernel<<<(B_*DIM*N_)/256, 256, 0, stream>>>(y2, ab, out);
}

// Round 7
// 272.417 us; speedup vs baseline: 2.2868x; 1.3886x over previous
//
#include <hip/hip_runtime.h>
#include <hip/hip_bf16.h>
#include <math.h>

// ---------------------------------------------------------------------------
// FeatureNet (DGCNN edge-conv block), MI355X / gfx950, round 7.
//
// Round-7 change: both 128x128 convs moved to bf16 MFMA (16x16x32).
//  * H tile staged transposed in LDS as Ht[p][c] bf16 with c-octet XOR(p&7)
//    swizzle (same involution on write and read).
//  * W pre-cast to bf16 [d][c]; each wave preloads its 8 A-fragments into
//    registers straight from global (L2-hot, 32 KB).
//  * y2 materialized as bf16 (halves traffic); stats from f32 accumulators.
//  * conv3 single pass: stats + per-point max/min over k -> ymm (f32),
//    bn3max epilogue applies folded BN3 via sign-selected extremum.
// kNN / finalize kernels unchanged from round 6.
// ---------------------------------------------------------------------------

#define B_   16
#define N_   2048
#define KNN  8
#define DIM  128
#define P_   (B_*N_*KNN)   // 262144
#define CAP  128
#define NBLK 2048          // conv blocks (128 p each)

typedef __attribute__((ext_vector_type(8))) short bf16x8;
typedef __attribute__((ext_vector_type(4))) float f32x4;

// ws layout (bytes)
#define OFF_G     0ull
#define SZ_G      ((size_t)3*P_*4)             // 3,145,728
#define OFF_Y2B   (OFF_G + SZ_G)
#define SZ_Y2B    ((size_t)DIM*P_*2)           // 67,108,864
#define OFF_WB2   (OFF_Y2B + SZ_Y2B)
#define SZ_WB     ((size_t)DIM*DIM*2)          // 32,768
#define OFF_WB3   (OFF_WB2 + SZ_WB)
#define OFF_STATS (OFF_WB3 + SZ_WB)
#define N_STATS   4112
#define SZ_STATS  ((size_t)N_STATS*8)
#define OFF_AB    (OFF_STATS + SZ_STATS)
#define SZ_AB     4096ull
#define OFF_KPART (OFF_AB + SZ_AB)
#define NKBLK     2048
#define SZ_KPART  ((size_t)9*NKBLK*4)
#define OFF_YMM   (OFF_KPART + SZ_KPART)
#define SZ_YMM    ((size_t)DIM*NBLK*32*4)      // 33,554,432

// stats (f64) indices
#define I_S2   16
#define I_S3   (16 + 8*256)
#define NBANK  8

// ab (float) layout
#define AB_W1F 0
#define AB_A2  512
#define AB_E2  640
#define AB_A3  768
#define AB_E3  896

__device__ __forceinline__ void atomAddD(double* p, double v) {
    __hip_atomic_fetch_add(p, v, __ATOMIC_RELAXED, __HIP_MEMORY_SCOPE_AGENT);
}
__device__ __forceinline__ unsigned short f2bs(float f) {
    const unsigned b = __float_as_uint(f);
    return (unsigned short)((b + 0x7FFFu + ((b >> 16) & 1u)) >> 16);   // RNE
}
__device__ __forceinline__ float bs2f(unsigned short u) {
    return __uint_as_float(((unsigned)u) << 16);
}

// ---------------------------------------------------------------------------
__global__ void zero_stats_kernel(double* __restrict__ st) {
    for (int i = threadIdx.x; i < N_STATS; i += 256) st[i] = 0.0;
}

// W2/W3 f32 [d][c] -> bf16 [d][c]
__global__ __launch_bounds__(256) void castW_kernel(
    const float* __restrict__ W2, const float* __restrict__ W3,
    unsigned short* __restrict__ Wb2, unsigned short* __restrict__ Wb3)
{
    const int i = blockIdx.x * 256 + threadIdx.x;   // 0..16383
    Wb2[i] = f2bs(W2[i]);
    Wb3[i] = f2bs(W3[i]);
}

// ---------------------------------------------------------------------------
// kNN + grouped offsets + layer-1 moment partials (round-6 proven version).
__global__ __launch_bounds__(1024) void knn_group_kernel(
    const float* __restrict__ x, float* __restrict__ g, float* __restrict__ kpart)
{
    __shared__ float xsx[N_], xsy[N_], xsz[N_], xsq[N_];
    __shared__ float listD[16][CAP];
    __shared__ int   listI[16][CAP];
    __shared__ float spart[16][12];
    const int b   = blockIdx.y;
    const int tid = threadIdx.x;
    const int wv  = tid >> 6;
    const int ln  = tid & 63;
    const int n   = blockIdx.x * 16 + wv;
    const float* xb = x + (size_t)b * 3 * N_;

    for (int i = tid; i < N_; i += 1024) {
        const float a0 = xb[i], a1 = xb[N_ + i], a2 = xb[2*N_ + i];
        const float sq = __fadd_rn(__fadd_rn(__fmul_rn(a0,a0), __fmul_rn(a1,a1)), __fmul_rn(a2,a2));
        xsx[i] = a0; xsy[i] = a1; xsz[i] = a2; xsq[i] = sq;
    }
    __syncthreads();

    const float xn0 = xsx[n], xn1 = xsy[n], xn2 = xsz[n], sqn = xsq[n];

    float dreg[32];
    float lmin = INFINITY;
    #pragma unroll
    for (int i = 0; i < 32; ++i) {
        const int m = ln + 64*i;
        const float qx = xsx[m], qy = xsy[m], qz = xsz[m], qw = xsq[m];
        dreg[i] = __fadd_rn(__fmaf_rn(-2.f, __fmaf_rn(xn2, qz, __fmaf_rn(xn1, qy, __fmul_rn(xn0, qx))), sqn), qw);
        lmin = fminf(lmin, dreg[i]);
    }

    float t = lmin, B = lmin;
    #pragma unroll
    for (int s = 0; s < 8; ++s) {
        float cur = t;
        #pragma unroll
        for (int m = 1; m < 64; m <<= 1) cur = fminf(cur, __shfl_xor(cur, m));
        B = cur;
        t = (t == cur) ? INFINITY : t;
    }

    unsigned base = 0;
    #pragma unroll
    for (int i = 0; i < 32; ++i) {
        const bool pred = (dreg[i] <= B);
        const unsigned long long mk = __ballot(pred);
        if (pred) {
            const unsigned pos = base + (unsigned)__popcll(mk & ((1ull << ln) - 1ull));
            if (pos < CAP) { listD[wv][pos] = dreg[i]; listI[wv][pos] = ln + 64*i; }
        }
        base += (unsigned)__popcll(mk);
    }
    const int cnt = (base < CAP) ? (int)base : CAP;

    float cd0 = (ln < cnt)      ? listD[wv][ln]      : INFINITY;
    int   ci0 = (ln < cnt)      ? listI[wv][ln]      : 0x7FFFFFFF;
    float cd1 = (ln + 64 < cnt) ? listD[wv][ln + 64] : INFINITY;
    int   ci1 = (ln + 64 < cnt) ? listI[wv][ln + 64] : 0x7FFFFFFF;
    int myi = 0;
    #pragma unroll
    for (int sel = 0; sel < 8; ++sel) {
        const bool sw = (cd1 < cd0) || (cd1 == cd0 && ci1 < ci0);
        float pd = sw ? cd1 : cd0;
        int   pi = sw ? ci1 : ci0;
        #pragma unroll
        for (int m = 1; m < 64; m <<= 1) {
            const float od = __shfl_xor(pd, m);
            const int   oi = __shfl_xor(pi, m);
            if ((od < pd) || (od == pd && oi < pi)) { pd = od; pi = oi; }
        }
        myi = (ln == sel) ? pi : myi;
        if (ci0 == pi) cd0 = INFINITY;
        if (ci1 == pi) cd1 = INFINITY;
    }

    if (ln < 8) {
        const float g0  = xsx[myi] - xn0;
        const float g1v = xsy[myi] - xn1;
        const float g2v = xsz[myi] - xn2;
        const size_t basep = ((size_t)b*N_ + n) * KNN;
        g[0*P_ + basep + ln] = g0;
        g[1*P_ + basep + ln] = g1v;
        g[2*P_ + basep + ln] = g2v;
        float s0 = g0, s1 = g1v, s2 = g2v;
        float s00 = g0*g0, s01 = g0*g1v, s02 = g0*g2v;
        float s11 = g1v*g1v, s12 = g1v*g2v, s22 = g2v*g2v;
        #pragma unroll
        for (int m = 1; m < 8; m <<= 1) {
            s0 += __shfl_xor(s0, m);  s1 += __shfl_xor(s1, m);  s2 += __shfl_xor(s2, m);
            s00 += __shfl_xor(s00, m); s01 += __shfl_xor(s01, m); s02 += __shfl_xor(s02, m);
            s11 += __shfl_xor(s11, m); s12 += __shfl_xor(s12, m); s22 += __shfl_xor(s22, m);
        }
        if (ln == 0) {
            spart[wv][0] = s0;  spart[wv][1] = s1;  spart[wv][2] = s2;
            spart[wv][3] = s00; spart[wv][4] = s01; spart[wv][5] = s02;
            spart[wv][6] = s11; spart[wv][7] = s12; spart[wv][8] = s22;
        }
    }
    __syncthreads();
    if (tid < 9) {
        float a = 0.f;
        #pragma unroll
        for (int w = 0; w < 16; ++w) a += spart[w][tid];
        kpart[tid*NKBLK + blockIdx.y*128 + blockIdx.x] = a;
    }
}

// ---------------------------------------------------------------------------
__global__ __launch_bounds__(128) void finalize1_kernel(
    const float* __restrict__ kpart, const float* __restrict__ W1,
    const float* __restrict__ b1, const float* __restrict__ g1,
    const float* __restrict__ be1, float* __restrict__ ab)
{
    __shared__ double red[128];
    __shared__ double S9[9];
    const int tid = threadIdx.x;
    for (int m = 0; m < 9; ++m) {
        double a = 0.0;
        for (int i = tid; i < NKBLK; i += 128) a += (double)kpart[m*NKBLK + i];
        red[tid] = a;
        __syncthreads();
        if (tid == 0) {
            double s = 0.0;
            for (int j = 0; j < 128; ++j) s += red[j];
            S9[m] = s;
        }
        __syncthreads();
    }
    const int d = tid;
    const double inv = 1.0 / (double)P_;
    const double mu0 = S9[0]*inv, mu1 = S9[1]*inv, mu2 = S9[2]*inv;
    const double c00 = S9[3]*inv - mu0*mu0;
    const double c01 = S9[4]*inv - mu0*mu1;
    const double c02 = S9[5]*inv - mu0*mu2;
    const double c11 = S9[6]*inv - mu1*mu1;
    const double c12 = S9[7]*inv - mu1*mu2;
    const double c22 = S9[8]*inv - mu2*mu2;
    const double w0 = W1[d*3+0], w1 = W1[d*3+1], w2 = W1[d*3+2];
    const double mean = w0*mu0 + w1*mu1 + w2*mu2 + (double)b1[d];
    double var = w0*w0*c00 + w1*w1*c11 + w2*w2*c22
               + 2.0*(w0*w1*c01 + w0*w2*c02 + w1*w2*c12);
    if (var < 0.0) var = 0.0;
    const double r = 1.0 / sqrt(var + 1e-5);
    const double alpha = (double)g1[d] * r;
    const double beta  = (double)be1[d] - mean*alpha;
    ab[AB_W1F + 4*d + 0] = (float)(alpha * w0);
    ab[AB_W1F + 4*d + 1] = (float)(alpha * w1);
    ab[AB_W1F + 4*d + 2] = (float)(alpha * w2);
    ab[AB_W1F + 4*d + 3] = (float)(alpha * (double)b1[d] + beta);
}

__global__ void finalize23_kernel(
    const double* __restrict__ st, int soff,
    const float* __restrict__ gg, const float* __restrict__ bee,
    float* __restrict__ ab, int aoff)
{
    const int d = threadIdx.x;
    if (d >= DIM) return;
    double s1 = 0.0, s2 = 0.0;
    #pragma unroll
    for (int k = 0; k < NBANK; ++k) {
        s1 += st[soff + k*256 + d];
        s2 += st[soff + k*256 + 128 + d];
    }
    const double inv = 1.0 / (double)P_;
    const double mean = s1 * inv;
    double var = s2 * inv - mean*mean;
    if (var < 0.0) var = 0.0;
    const double r = 1.0 / sqrt(var + 1e-5);
    const double alpha = (double)gg[d] * r;
    ab[aoff + d]       = (float)alpha;
    ab[aoff + 128 + d] = (float)((double)bee[d] - mean*alpha);
}

// ---------------------------------------------------------------------------
// MFMA conv: block = 128d x 128p tile, 4 waves; wave w owns d in [32w,32w+32).
// Ht[p][c] bf16 in LDS, c-octet slot XOR'ed with (p&7) (write & read agree).
// A-frags preloaded from global bf16 W[d][c] (8 x b128 per lane, L2-hot).
// mfma_f32_16x16x32_bf16: D col=lane&15 (p), row=4*(lane>>4)+reg (d offset).
// SRC 0: H from g via folded W1f (conv2).  SRC 1: H = relu(a2*y2b+e2) (conv3).
// MODE 0: y2b (bf16) + stats.  MODE 3: stats + per-point max/min -> ymm.
template<int SRC, int MODE>
__global__ __launch_bounds__(256) void conv_kernel(
    const float* __restrict__ gsrc, const unsigned short* __restrict__ ybsrc,
    const unsigned short* __restrict__ Wb, const float* __restrict__ ab,
    const float* __restrict__ bias, unsigned short* __restrict__ ybdst,
    float* __restrict__ ymm, double* __restrict__ stats, int statoff)
{
    __shared__ __align__(16) short Hs[128*128];   // 32 KB, Ht[p][c] swizzled
    const int tid = threadIdx.x;
    const int p0g = blockIdx.x * 128;
    const int w  = tid >> 6, ln = tid & 63;
    const int lg = ln >> 4, lr = ln & 15;

    // ---- A-fragment preload (issue early; consumed after barrier)
    bf16x8 afrag[2][4];
    #pragma unroll
    for (int dtl = 0; dtl < 2; ++dtl)
        #pragma unroll
        for (int ks = 0; ks < 4; ++ks)
            afrag[dtl][ks] = *(const bf16x8*)&Wb[(32*w + 16*dtl + lr)*DIM + (4*ks + lg)*8];

    // ---- stage Ht: thread owns row sp, octets ob, ob+2, ..., ob+14
    const int sp = 64*(w & 1) + ln;     // 0..127
    const int ob = w >> 1;              // 0 or 1
    if constexpr (SRC == 0) {
        const float gx = gsrc[0*P_ + p0g + sp];
        const float gy = gsrc[1*P_ + p0g + sp];
        const float gz = gsrc[2*P_ + p0g + sp];
        #pragma unroll
        for (int it = 0; it < 8; ++it) {
            const int o = ob + 2*it;
            bf16x8 hv;
            #pragma unroll
            for (int j = 0; j < 8; ++j) {
                const int c = 8*o + j;
                const float4 wf = *(const float4*)&ab[AB_W1F + 4*c];
                const float h = fmaxf(__fmaf_rn(wf.x, gx, __fmaf_rn(wf.y, gy, __fmaf_rn(wf.z, gz, wf.w))), 0.f);
                hv[j] = (short)f2bs(h);
            }
            *(bf16x8*)&Hs[sp*128 + ((o ^ (sp & 7)) * 8)] = hv;
        }
    } else {
        #pragma unroll
        for (int it = 0; it < 8; ++it) {
            const int o = ob + 2*it;
            bf16x8 hv;
            #pragma unroll
            for (int j = 0; j < 8; ++j) {
                const int c = 8*o + j;
                const float v = bs2f(ybsrc[(size_t)c*P_ + p0g + sp]);
                const float h = fmaxf(__fmaf_rn(ab[AB_A2 + c], v, ab[AB_E2 + c]), 0.f);
                hv[j] = (short)f2bs(h);
            }
            *(bf16x8*)&Hs[sp*128 + ((o ^ (sp & 7)) * 8)] = hv;
        }
    }
    __syncthreads();

    // ---- MFMA main: acc[dtl][pt], 64 MFMAs/wave
    f32x4 acc[2][8];
    #pragma unroll
    for (int i = 0; i < 2; ++i)
        #pragma unroll
        for (int j = 0; j < 8; ++j)
            acc[i][j] = (f32x4){0.f, 0.f, 0.f, 0.f};

    #pragma unroll
    for (int ks = 0; ks < 4; ++ks) {
        #pragma unroll
        for (int pt = 0; pt < 8; ++pt) {
            const int p = 16*pt + lr;
            const bf16x8 bf = *(const bf16x8*)&Hs[p*128 + (((4*ks + lg) ^ (lr & 7)) * 8)];
            acc[0][pt] = __builtin_amdgcn_mfma_f32_16x16x32_bf16(afrag[0][ks], bf, acc[0][pt], 0, 0, 0);
            acc[1][pt] = __builtin_amdgcn_mfma_f32_16x16x32_bf16(afrag[1][ks], bf, acc[1][pt], 0, 0, 0);
        }
    }

    // ---- epilogue
    const int bank = blockIdx.x & (NBANK-1);
    #pragma unroll
    for (int dtl = 0; dtl < 2; ++dtl) {
        #pragma unroll
        for (int r = 0; r < 4; ++r) {
            const int d = 32*w + 16*dtl + 4*lg + r;
            const float bb = bias[d];
            float v[8];
            #pragma unroll
            for (int pt = 0; pt < 8; ++pt) v[pt] = acc[dtl][pt][r] + bb;

            if constexpr (MODE == 0) {
                #pragma unroll
                for (int pt = 0; pt < 8; ++pt)
                    ybdst[(size_t)d*P_ + p0g + 16*pt + lr] = f2bs(v[pt]);
            }

            float s1 = ((v[0]+v[1])+(v[2]+v[3])) + ((v[4]+v[5])+(v[6]+v[7]));
            float s2 = ((v[0]*v[0]+v[1]*v[1])+(v[2]*v[2]+v[3]*v[3]))
                     + ((v[4]*v[4]+v[5]*v[5])+(v[6]*v[6]+v[7]*v[7]));
            #pragma unroll
            for (int m = 1; m < 16; m <<= 1) { s1 += __shfl_xor(s1, m); s2 += __shfl_xor(s2, m); }
            if (lr == 0) {
                atomAddD(&stats[statoff + bank*256 + d], (double)s1);
                atomAddD(&stats[statoff + bank*256 + 128 + d], (double)s2);
            }

            if constexpr (MODE == 3) {
                #pragma unroll
                for (int pt = 0; pt < 8; ++pt) {
                    float mx = v[pt], mn = v[pt];
                    float o1 = __shfl_xor(mx, 1); mx = fmaxf(mx, o1); mn = fminf(mn, o1);
                    float o2x = __shfl_xor(mx, 2), o2n = __shfl_xor(mn, 2);
                    mx = fmaxf(mx, o2x); mn = fminf(mn, o2n);
                    float o4x = __shfl_xor(mx, 4), o4n = __shfl_xor(mn, 4);
                    mx = fmaxf(mx, o4x); mn = fminf(mn, o4n);
                    if ((lr & 7) == 0) {
                        const int slot = 2*pt + (lr >> 3);
                        float* yb = ymm + ((size_t)d*NBLK + blockIdx.x)*32;
                        yb[slot]      = mx;
                        yb[16 + slot] = mn;
                    }
                }
            }
        }
    }
}

// ---------------------------------------------------------------------------
// Epilogue: out[b,d,n] = relu(a3*(a3>=0 ? max_k : min_k) + e3)
__global__ __launch_bounds__(256) void bn3max_kernel(
    const float* __restrict__ ymm, const float* __restrict__ ab, float* __restrict__ out)
{
    const int idx = blockIdx.x*256 + threadIdx.x;   // over B*DIM*N
    const int n = idx & (N_-1);
    const int d = (idx >> 11) & (DIM-1);
    const int b = idx >> 18;
    const int pt  = b*N_ + n;
    const int blk = pt >> 4;
    const int j   = pt & 15;
    const size_t base = ((size_t)d*NBLK + blk) * 32;
    const float a = ab[AB_A3 + d], e = ab[AB_E3 + d];
    const float mx = ymm[base + j];
    const float mn = ymm[base + 16 + j];
    const float v = (a >= 0.f) ? mx : mn;
    out[idx] = fmaxf(__fmaf_rn(a, v, e), 0.f);
}

// ---------------------------------------------------------------------------
extern "C" void kernel_launch(void* const* d_in, const int* in_sizes, int n_in,
                              void* d_out, int out_size, void* d_ws, size_t ws_size,
                              hipStream_t stream) {
    (void)in_sizes; (void)n_in; (void)out_size; (void)ws_size;
    const float* x   = (const float*)d_in[0];
    const float* W1  = (const float*)d_in[1];
    const float* b1  = (const float*)d_in[2];
    const float* g1  = (const float*)d_in[3];
    const float* be1 = (const float*)d_in[4];
    const float* W2  = (const float*)d_in[5];
    const float* b2  = (const float*)d_in[6];
    const float* g2  = (const float*)d_in[7];
    const float* be2 = (const float*)d_in[8];
    const float* W3  = (const float*)d_in[9];
    const float* b3  = (const float*)d_in[10];
    const float* g3  = (const float*)d_in[11];
    const float* be3 = (const float*)d_in[12];

    float*  out = (float*)d_out;
    char*   ws  = (char*)d_ws;
    float*          g   = (float*)(ws + OFF_G);
    unsigned short* y2b = (unsigned short*)(ws + OFF_Y2B);
    unsigned short* wb2 = (unsigned short*)(ws + OFF_WB2);
    unsigned short* wb3 = (unsigned short*)(ws + OFF_WB3);
    double*         st  = (double*)(ws + OFF_STATS);
    float*          ab  = (float*)(ws + OFF_AB);
    float*          kp  = (float*)(ws + OFF_KPART);
    float*          ymm = (float*)(ws + OFF_YMM);

    zero_stats_kernel<<<1, 256, 0, stream>>>(st);
    castW_kernel<<<64, 256, 0, stream>>>(W2, W3, wb2, wb3);
    knn_group_kernel<<<dim3(128, B_), 1024, 0, stream>>>(x, g, kp);
    finalize1_kernel<<<1, 128, 0, stream>>>(kp, W1, b1, g1, be1, ab);
    conv_kernel<0,0><<<NBLK, 256, 0, stream>>>(g, nullptr, wb2, ab, b2, y2b, nullptr, st, I_S2);
    finalize23_kernel<<<1, 128, 0, stream>>>(st, I_S2, g2, be2, ab, AB_A2);
    conv_kernel<1,3><<<NBLK, 256, 0, stream>>>(nullptr, y2b, wb3, ab, b3, nullptr, ymm, st, I_S3);
    finalize23_kernel<<<1, 128, 0, stream>>>(st, I_S3, g3, be3, ab, AB_A3);
    bn3max_kernel<<<(B_*DIM*N_)/256, 256, 0, stream>>>(ymm, ab, out);
}